// Round 12
// baseline (451.650 us; speedup 1.0000x reference)
//
#include <hip/hip_runtime.h>
#include <hip/hip_cooperative_groups.h>

namespace cg = cooperative_groups;

#define B_ 4
#define N_ 2048
#define K_ 32
#define CIN_ 16
#define COUT_ 32
#define H_ 32
#define R_ (B_*N_*K_)
#define EPS_ 1e-5f
#define INVR_ (1.0f/(float)R_)
#define INVBN_ (1.0f/(float)(B_*N_))
#define LISTCAP 112
#define NSH 16

typedef __attribute__((ext_vector_type(8)))  _Float16 f16x8;
typedef __attribute__((ext_vector_type(2)))  __fp16   hw16x2;
typedef __attribute__((ext_vector_type(2)))  _Float16 f16x2;
typedef __attribute__((ext_vector_type(16))) float    f32x16;

__device__ __forceinline__ float dot3f(float ax,float ay,float az,float bx,float by,float bz){
    return fmaf(az,bz, fmaf(ay,by, ax*bx));
}
__device__ __forceinline__ unsigned int pk2(float a, float b){
    union { hw16x2 v; unsigned int u; } c;
    c.v = __builtin_amdgcn_cvt_pkrtz(a, b);
    return c.u;
}
__device__ __forceinline__ unsigned int pkmul(unsigned int a, unsigned int b){
    union { unsigned int u; f16x2 v; } x, y, r;
    x.u = a; y.u = b; r.v = x.v * y.v; return r.u;
}
__device__ __forceinline__ float shsum(const float* __restrict__ p, int k){
    float s = 0.f;
    #pragma unroll
    for (int i = 0; i < NSH; ++i) s += p[i*32 + k];
    return s;
}

union SharedMem {
    struct {
        unsigned int hist[4][512][2];         // 16 KB
        unsigned long long lst[4][LISTCAP];   // 3.5 KB
        int kidx[4][K_];                      // 0.5 KB
    } knn;
    struct {
        float redS[32], redQ[32];
    } red;
};

__global__ __launch_bounds__(256,3) void k_mega(
        const float* __restrict__ xyz, const float* __restrict__ points,
        const float* __restrict__ W1, const float* __restrict__ b1,
        const float* __restrict__ g1, const float* __restrict__ be1,
        const float* __restrict__ W2, const float* __restrict__ b2,
        const float* __restrict__ g2, const float* __restrict__ be2,
        const float* __restrict__ W3, const float* __restrict__ b3,
        const float* __restrict__ gbn, const float* __restrict__ bbn,
        float* __restrict__ out, char* __restrict__ base)
{
    cg::grid_group grid = cg::this_grid();

    int*            idx     = (int*)(base);
    float*          out_pre = (float*)(base + 1048576);
    unsigned int*   pf16    = (unsigned int*)(base + 2097152);
    unsigned int*   W3f     = (unsigned int*)(base + 2359296);
    float*          st      = (float*)(base + 2393088);
    float4*         xs4g    = (float4*)(base + 2398208);
    unsigned int*   W2fg    = (unsigned int*)(base + 2529280);
    float*          b2pg    = (float*)(base + 2531328);
    float *s1s = st, *q1s = st+512, *s2 = st+1024, *q2 = st+1056, *s3 = st+1088, *q3 = st+1120;

    const int tid  = threadIdx.x;
    const int blk  = blockIdx.x;
    const int nb   = gridDim.x;
    const int nthr = nb * 256;
    const int lane = tid & 63, w = tid >> 6;
    const int half = lane >> 5, m = lane & 31;

    __shared__ SharedMem sh;

    // ---------------- Phase A: prep (xs4g, pf16, zero stats) ----------------
    for (int i = blk*256 + tid; i < 65536; i += nthr)
        pf16[i] = pk2(points[2*i], points[2*i+1]);
    for (int i = blk*256 + tid; i < B_*N_; i += nthr){
        float x = xyz[3*i], y = xyz[3*i+1], z = xyz[3*i+2];
        xs4g[i] = make_float4(x, y, z, dot3f(x,y,z,x,y,z));
    }
    if (blk == 0) for (int j = tid; j < 1280; j += 256) st[j] = 0.f;
    grid.sync();

    // ---------------- Phase B: KNN (R10 body, wave-autonomous, grid-strided) ----------------
    {
        const int nwav = nb * 4;
        for (int qg = blk*4 + w; qg < B_*N_; qg += nwav){
            const int b_ = qg >> 11;
            const int q  = qg & (N_-1);
            const int bN = b_ * N_;
            unsigned int* hw = &sh.knn.hist[w][0][0];

            const uint4 z4 = make_uint4(0,0,0,0);
            uint4* h4 = (uint4*)hw;
            #pragma unroll
            for (int i = 0; i < 4; ++i) h4[i*64 + lane] = z4;

            const float4 qp = xs4g[bN + q];
            const float qx = qp.x, qy = qp.y, qz = qp.z, sqq = qp.w;

            unsigned int fv[32];
            #pragma unroll
            for (int j = 0; j < 32; ++j){
                int c = j*64 + lane;
                float4 pt = xs4g[bN + c];
                float d = fmaf(-2.0f, dot3f(qx,qy,qz, pt.x,pt.y,pt.z), sqq) + pt.w;
                fv[j] = __float_as_uint(d);
                unsigned int u1 = __float_as_uint(d + 1.0f);
                unsigned int key = (u1 <= 0x3F800000u) ? 0u : ((u1 - 0x3F800000u) >> 15);
                key = key > 511u ? 511u : key;
                atomicAdd(&hw[key*2 + (lane & 1)], 1u);
            }

            unsigned int g[8];
            #pragma unroll
            for (int t = 0; t < 4; ++t){
                uint4 h = ((const uint4*)hw)[lane*4 + t];
                g[2*t]   = h.x + h.y;
                g[2*t+1] = h.z + h.w;
            }
            unsigned int gs = 0;
            #pragma unroll
            for (int t = 0; t < 8; ++t) gs += g[t];
            unsigned int cum = gs;
            #pragma unroll
            for (int off = 1; off < 64; off <<= 1){
                unsigned int v = __shfl_up(cum, off);
                if (lane >= off) cum += v;
            }
            unsigned long long bal = __ballot(cum >= (unsigned)K_);
            int L = __ffsll(bal) - 1;
            unsigned int run = __shfl(cum, L) - __shfl(gs, L);
            int Bsel = 8*L + 7;
            {
                unsigned int c = run; bool fnd = false;
                #pragma unroll
                for (int t = 0; t < 8; ++t){
                    unsigned int ht = __shfl(g[t], L, 64);
                    if (!fnd && c + ht >= (unsigned)K_){ Bsel = 8*L + t; fnd = true; }
                    c += ht;
                }
            }
            const float Tedge = __uint_as_float(0x3F800000u + ((unsigned)(Bsel + 1) << 15));
            const bool allin = (Bsel == 511);

            const unsigned long long mlt = (lane == 63) ? ~0ull >> 1 : (1ull << lane) - 1ull;
            unsigned int cnt = 0;
            #pragma unroll
            for (int j = 0; j < 32; ++j){
                float f1 = __uint_as_float(fv[j]) + 1.0f;
                bool surv = (f1 < Tedge) || allin;
                unsigned long long sb = __ballot(surv);
                unsigned int pos = cnt + (unsigned int)__popcll(sb & mlt);
                if (surv && pos < (unsigned)LISTCAP)
                    sh.knn.lst[w][pos] = ((unsigned long long)fv[j] << 32) | (unsigned int)(j*64 + lane);
                cnt += (unsigned int)__popcll(sb);
            }
            int mc = (int)cnt; if (mc > LISTCAP) mc = LISTCAP;

            int* outp = idx + ((size_t)bN + q) * K_;
            for (int i = lane; i < mc; i += 64){
                unsigned long long my = sh.knn.lst[w][i];
                int rank = 0;
                for (int jj = 0; jj < mc; ++jj)
                    rank += (sh.knn.lst[w][jj] < my) ? 1 : 0;
                if (rank < K_){
                    int id = (int)(unsigned int)(my & 0xFFFFFFFFull);
                    outp[rank] = id;
                    sh.knn.kidx[w][rank] = id;
                }
            }

            {   // fused h1 stats
                const int ch = lane & 31;
                float w1a = W1[ch], w1b = W1[H_+ch], w1c = W1[2*H_+ch], b1c = b1[ch];
                float s = 0.f, qq = 0.f;
                #pragma unroll
                for (int r = 0; r < 16; ++r){
                    int idr = sh.knn.kidx[w][half*16 + r];
                    float4 pn = xs4g[bN + idr];
                    float rx = pn.x - qx, ry = pn.y - qy, rz = pn.z - qz;
                    float h = fmaxf(fmaf(rx, w1a, fmaf(ry, w1b, fmaf(rz, w1c, b1c))), 0.0f);
                    s += h; qq = fmaf(h, h, qq);
                }
                s  += __shfl_xor(s, 32, 64);
                qq += __shfl_xor(qq, 32, 64);
                if (lane < 32){
                    int shh = (qg & (NSH-1)) * 32 + ch;
                    atomicAdd(&s1s[shh], s);
                    atomicAdd(&q1s[shh], qq);
                }
            }
        }
    }
    grid.sync();

    // ---------------- Phase C: W2f + b2p (R10 prep2 numerics, grid-strided) ----------------
    for (int t = blk*256 + tid; t < 544; t += nthr){
        if (t < 512){
            int d = t, jj = d & 3, ln = (d >> 2) & 63, s = d >> 8;
            int col = ln & 31;
            int k0 = s*16 + (ln >> 5)*8 + 2*jj;
            float m0 = shsum(s1s,k0)*INVR_,   v0 = shsum(q1s,k0)*INVR_   - m0*m0;
            float m1 = shsum(s1s,k0+1)*INVR_, v1 = shsum(q1s,k0+1)*INVR_ - m1*m1;
            float a0  = g1[k0]   / sqrtf(v0 + EPS_);
            float a1v = g1[k0+1] / sqrtf(v1 + EPS_);
            W2fg[d] = pk2(a0*W2[k0*H_ + col], a1v*W2[(k0+1)*H_ + col]);
        } else {
            int col = t - 512;
            float acc = b2[col];
            #pragma unroll 4
            for (int h = 0; h < H_; ++h){
                float mm = shsum(s1s,h)*INVR_, vv = shsum(q1s,h)*INVR_ - mm*mm;
                float aa = g1[h] / sqrtf(vv + EPS_);
                float bb = fmaf(-aa, mm, be1[h]);
                acc = fmaf(bb, W2[h*H_ + col], acc);
            }
            b2pg[col] = acc;
        }
    }
    grid.sync();

    // ---------------- Phase D: h2 stats (R10 k_h2stats body, grid-strided) ----------------
    for (int u = blk; u < R_/256; u += nb){
        if (tid < H_){ sh.red.redS[tid] = 0.f; sh.red.redQ[tid] = 0.f; }
        __syncthreads();

        int r = u*256 + tid;
        float h1[H_];
        {
            int b_ = r >> 16, n = (r >> 5) & (N_-1), id = idx[r];
            float4 pc = xs4g[b_*N_ + n];
            float4 pn = xs4g[b_*N_ + id];
            float rx = pn.x - pc.x, ry = pn.y - pc.y, rz = pn.z - pc.z;
            #pragma unroll
            for (int j = 0; j < H_; ++j)
                h1[j] = fmaxf(fmaf(rx, W1[j], fmaf(ry, W1[H_+j], fmaf(rz, W1[2*H_+j], b1[j]))), 0.0f);
        }
        unsigned int h1p[16];
        #pragma unroll
        for (int i = 0; i < 16; ++i) h1p[i] = pk2(h1[2*i], h1[2*i+1]);

        union { uint4 u4; f16x8 v; } Bf0, Bf1;
        Bf0.u4 = ((const uint4*)W2fg)[lane];
        Bf1.u4 = ((const uint4*)W2fg)[64 + lane];
        float b2c = b2pg[m];

        float s = 0.f, q = 0.f;
        #pragma unroll
        for (int t = 0; t < 2; ++t){
            const int src = t*32 + m;
            union { unsigned int u[4]; f16x8 v; } a0, a1f;
            #pragma unroll
            for (int jj = 0; jj < 4; ++jj){
                unsigned int lo = __shfl(h1p[jj],     src, 64);
                unsigned int hi = __shfl(h1p[4 + jj], src, 64);
                a0.u[jj] = half ? hi : lo;
            }
            #pragma unroll
            for (int jj = 0; jj < 4; ++jj){
                unsigned int lo = __shfl(h1p[8 + jj],  src, 64);
                unsigned int hi = __shfl(h1p[12 + jj], src, 64);
                a1f.u[jj] = half ? hi : lo;
            }
            f32x16 acc;
            #pragma unroll
            for (int i = 0; i < 16; ++i) acc[i] = b2c;
            acc = __builtin_amdgcn_mfma_f32_32x32x16_f16(a0.v,  Bf0.v, acc, 0, 0, 0);
            acc = __builtin_amdgcn_mfma_f32_32x32x16_f16(a1f.v, Bf1.v, acc, 0, 0, 0);
            #pragma unroll
            for (int i = 0; i < 16; ++i){
                float v = fmaxf(acc[i], 0.0f);
                s += v; q = fmaf(v, v, q);
            }
        }
        s += __shfl_xor(s, 32, 64);
        q += __shfl_xor(q, 32, 64);
        if (lane < 32){ atomicAdd(&sh.red.redS[m], s); atomicAdd(&sh.red.redQ[m], q); }
        __syncthreads();
        if (tid < H_){ atomicAdd(&s2[tid], sh.red.redS[tid]); atomicAdd(&q2[tid], sh.red.redQ[tid]); }
    }
    grid.sync();

    // ---------------- Phase E: W3f (R10 prep3 numerics, grid-strided) ----------------
    for (int d = blk*256 + tid; d < 8448; d += nthr){
        int jj = d & 3, ln = (d >> 2) & 63, step = d >> 8;
        int col = ln & 31;
        int off = (ln >> 5)*8 + 2*jj;
        float v0, v1;
        if (step < 32){
            float mm = s2[step]*INVR_, vv = q2[step]*INVR_ - mm*mm;
            float aa = g2[step] / sqrtf(vv + EPS_);
            v0 = aa * W3[step*512 + off*COUT_ + col];
            v1 = aa * W3[step*512 + (off+1)*COUT_ + col];
        } else {
            v0 = b3[off*COUT_ + col]; v1 = b3[(off+1)*COUT_ + col];
            #pragma unroll 4
            for (int h = 0; h < H_; ++h){
                float mm = s2[h]*INVR_, vv = q2[h]*INVR_ - mm*mm;
                float aa = g2[h] / sqrtf(vv + EPS_);
                float bb = fmaf(-aa, mm, be2[h]);
                v0 = fmaf(bb, W3[h*512 + off*COUT_ + col], v0);
                v1 = fmaf(bb, W3[h*512 + (off+1)*COUT_ + col], v1);
            }
        }
        W3f[d] = pk2(v0, v1);
    }
    grid.sync();

    // ---------------- Phase F: k_out (R10 body, grid-strided) ----------------
    {
        union { uint4 u4; f16x8 v; } A0, A1;
        A0.u4 = ((const uint4*)W2fg)[lane];
        A1.u4 = ((const uint4*)W2fg)[64 + lane];
        float b2v[16];
        #pragma unroll
        for (int i = 0; i < 16; ++i) b2v[i] = b2pg[(i&3) + 8*(i>>2) + 4*half];
        const uint4* Wf = (const uint4*)W3f + lane;

        for (int u = blk; u < R_/256; u += nb){
            if (tid < COUT_){ sh.red.redS[tid] = 0.f; sh.red.redQ[tid] = 0.f; }
            __syncthreads();

            const int rB = u*256 + w*64;
            int r = u*256 + tid;
            float h1[H_];
            {
                int b_ = r >> 16, n = (r >> 5) & (N_-1), id = idx[r];
                float4 pc = xs4g[b_*N_ + n];
                float4 pn = xs4g[b_*N_ + id];
                float rx = pn.x - pc.x, ry = pn.y - pc.y, rz = pn.z - pc.z;
                #pragma unroll
                for (int j = 0; j < H_; ++j)
                    h1[j] = fmaxf(fmaf(rx, W1[j], fmaf(ry, W1[H_+j], fmaf(rz, W1[2*H_+j], b1[j]))), 0.0f);
            }
            unsigned int h1p[16];
            #pragma unroll
            for (int i = 0; i < 16; ++i) h1p[i] = pk2(h1[2*i], h1[2*i+1]);

            #pragma unroll
            for (int t = 0; t < 2; ++t){
                const int src = t*32 + m;
                union { unsigned int u[4]; f16x8 v; } B0f, B1f;
                #pragma unroll
                for (int jj = 0; jj < 4; ++jj){
                    unsigned int lo = __shfl(h1p[jj],     src, 64);
                    unsigned int hi = __shfl(h1p[4 + jj], src, 64);
                    B0f.u[jj] = half ? hi : lo;
                }
                #pragma unroll
                for (int jj = 0; jj < 4; ++jj){
                    unsigned int lo = __shfl(h1p[8 + jj],  src, 64);
                    unsigned int hi = __shfl(h1p[12 + jj], src, 64);
                    B1f.u[jj] = half ? hi : lo;
                }
                f32x16 c2;
                #pragma unroll
                for (int i = 0; i < 16; ++i) c2[i] = b2v[i];
                c2 = __builtin_amdgcn_mfma_f32_32x32x16_f16(A0.v, B0f.v, c2, 0, 0, 0);
                c2 = __builtin_amdgcn_mfma_f32_32x32x16_f16(A1.v, B1f.v, c2, 0, 0, 0);

                unsigned int h2p[16];
                #pragma unroll
                for (int p = 0; p < 8; ++p){
                    float v0 = fmaxf(c2[2*p],   0.0f);
                    float v1 = fmaxf(c2[2*p+1], 0.0f);
                    unsigned int ow = pk2(v0, v1);
                    unsigned int ot = __shfl_xor(ow, 32, 64);
                    int a = p >> 1, bb = p & 1;
                    h2p[4*a + 2*half     + bb] = ow;
                    h2p[4*a + 2*(1-half) + bb] = ot;
                }

                int row = rB + t*32 + m;
                int bb_ = row >> 16;
                int idr = idx[row];
                const uint4* gpp = (const uint4*)(pf16 + ((size_t)bb_*N_ + idr)*8);
                uint4 ga = gpp[0], gb = gpp[1];
                unsigned int gsel[4];
                gsel[0] = half ? gb.x : ga.x;
                gsel[1] = half ? gb.y : ga.y;
                gsel[2] = half ? gb.z : ga.z;
                gsel[3] = half ? gb.w : ga.w;

                f32x16 acc;
                #pragma unroll
                for (int i = 0; i < 16; ++i) acc[i] = 0.f;
                #pragma unroll
                for (int kb = 0; kb < 32; ++kb){
                    unsigned int hr = h2p[kb >> 1];
                    unsigned int hd = __builtin_amdgcn_perm(hr, hr, (kb & 1) ? 0x03020302u : 0x01000100u);
                    union { unsigned int u[4]; f16x8 v; } af;
                    #pragma unroll
                    for (int jj = 0; jj < 4; ++jj) af.u[jj] = pkmul(hd, gsel[jj]);
                    union { uint4 u4; f16x8 v; } bf; bf.u4 = Wf[kb*64];
                    acc = __builtin_amdgcn_mfma_f32_32x32x16_f16(af.v, bf.v, acc, 0, 0, 0);
                }
                {
                    union { unsigned int u[4]; f16x8 v; } af;
                    #pragma unroll
                    for (int jj = 0; jj < 4; ++jj) af.u[jj] = gsel[jj];
                    union { uint4 u4; f16x8 v; } bf; bf.u4 = Wf[32*64];
                    acc = __builtin_amdgcn_mfma_f32_32x32x16_f16(af.v, bf.v, acc, 0, 0, 0);
                }

                float v = acc[0];
                #pragma unroll
                for (int i = 1; i < 16; ++i) v = fmaxf(v, acc[i]);
                v = fmaxf(v, __shfl_xor(v, 32, 64));
                if (lane < 32){
                    int gidx = u*8 + w*2 + t;
                    out_pre[(size_t)gidx*COUT_ + m] = v;
                    atomicAdd(&sh.red.redS[m], v);
                    atomicAdd(&sh.red.redQ[m], v*v);
                }
            }
            __syncthreads();
            if (tid < COUT_){ atomicAdd(&s3[tid], sh.red.redS[tid]); atomicAdd(&q3[tid], sh.red.redQ[tid]); }
        }
    }
    grid.sync();

    // ---------------- Phase G: final BN ----------------
    for (int i = blk*256 + tid; i < B_*N_*COUT_; i += nthr){
        int o = i & (COUT_-1);
        float mm = s3[o] * INVBN_;
        float vv = q3[o] * INVBN_ - mm*mm;
        float aa = gbn[o] / sqrtf(vv + EPS_);
        out[i] = fmaf(aa, out_pre[i], fmaf(-aa, mm, bbn[o]));
    }
}

extern "C" void kernel_launch(void* const* d_in, const int* in_sizes, int n_in,
                              void* d_out, int out_size, void* d_ws, size_t ws_size,
                              hipStream_t stream){
    const float* xyz    = (const float*)d_in[0];
    const float* points = (const float*)d_in[1];
    const float* W1  = (const float*)d_in[2];
    const float* b1  = (const float*)d_in[3];
    const float* g1  = (const float*)d_in[4];
    const float* be1 = (const float*)d_in[5];
    const float* W2  = (const float*)d_in[6];
    const float* b2  = (const float*)d_in[7];
    const float* g2  = (const float*)d_in[8];
    const float* be2 = (const float*)d_in[9];
    const float* W3  = (const float*)d_in[10];
    const float* b3  = (const float*)d_in[11];
    const float* gbn = (const float*)d_in[12];
    const float* bbn = (const float*)d_in[13];
    float* out = (float*)d_out;
    char* base = (char*)d_ws;

    int occ = 0;
    hipOccupancyMaxActiveBlocksPerMultiprocessor(&occ, k_mega, 256, 0);
    if (occ < 1) occ = 1;
    if (occ > 8) occ = 8;
    dim3 grid(occ * 256), block(256);

    void* args[] = {
        (void*)&xyz, (void*)&points, (void*)&W1, (void*)&b1, (void*)&g1, (void*)&be1,
        (void*)&W2, (void*)&b2, (void*)&g2, (void*)&be2, (void*)&W3, (void*)&b3,
        (void*)&gbn, (void*)&bbn, (void*)&out, (void*)&base
    };
    hipLaunchCooperativeKernel(k_mega, grid, block, args, 0, stream);
}

// Round 13
// 236.220 us; speedup vs baseline: 1.9120x; 1.9120x over previous
//
#include <hip/hip_runtime.h>

#define B_ 4
#define N_ 2048
#define K_ 32
#define CIN_ 16
#define COUT_ 32
#define H_ 32
#define R_ (B_*N_*K_)      // 262144 rows through the weight-net
#define EPS_ 1e-5f
#define INVR_ (1.0f/(float)R_)
#define INVBN_ (1.0f/(float)(B_*N_))
#define LISTCAP 112
#define NSH 16             // stat shadows

typedef __attribute__((ext_vector_type(8)))  _Float16 f16x8;
typedef __attribute__((ext_vector_type(2)))  __fp16   hw16x2;   // builtin cvt_pkrtz return type
typedef __attribute__((ext_vector_type(2)))  _Float16 f16x2;
typedef __attribute__((ext_vector_type(16))) float    f32x16;

__device__ __forceinline__ float dot3f(float ax,float ay,float az,float bx,float by,float bz){
    return fmaf(az,bz, fmaf(ay,by, ax*bx));
}
__device__ __forceinline__ unsigned int pk2(float a, float b){   // packed f16 pair (RTZ)
    union { hw16x2 v; unsigned int u; } c;
    c.v = __builtin_amdgcn_cvt_pkrtz(a, b);
    return c.u;
}
__device__ __forceinline__ unsigned int pkmul(unsigned int a, unsigned int b){  // v_pk_mul_f16
    union { unsigned int u; f16x2 v; } x, y, r;
    x.u = a; y.u = b; r.v = x.v * y.v; return r.u;
}
// sum of NSH shadow accumulators via agent-scope atomic loads (for last-block tails)
__device__ __forceinline__ float shsum_at(const float* __restrict__ p, int k){
    float s = 0.f;
    #pragma unroll
    for (int i = 0; i < NSH; ++i)
        s += __hip_atomic_load(&p[i*32 + k], __ATOMIC_RELAXED, __HIP_MEMORY_SCOPE_AGENT);
    return s;
}

// ---- prep0: pf16 (points->f16 pairs), xs4g, zero stats+counters ----
__global__ __launch_bounds__(256) void k_prep0(const float* __restrict__ xyz, const float* __restrict__ points,
                                               float4* __restrict__ xs4g, unsigned int* __restrict__ pf16,
                                               float* __restrict__ st){
    int i = blockIdx.x*256 + threadIdx.x;      // 256 blocks x 256 = 65536
    pf16[i] = pk2(points[2*i], points[2*i+1]);
    if (i < 8192){
        float x = xyz[3*i], y = xyz[3*i+1], z = xyz[3*i+2];
        xs4g[i] = make_float4(x, y, z, dot3f(x,y,z,x,y,z));
    }
    if (blockIdx.x == 0){
        for (int j = threadIdx.x; j < 1280; j += 256) st[j] = 0.f;
    }
}

// ---------------- KNN: 1 wave/query, wave-autonomous, single-pass linear-bucket histogram ----------------
// (256,6): (256,8) capped VGPR at 64 -> pass-1's 32 float4 loads lost MLP (round-9 lesson).
// Last block appends the W2f/b2p build (prep2 fold) — R11 lesson: tails are cheap, per-block prologs are not.
__global__ __launch_bounds__(256,6) void k_knn(const float4* __restrict__ xs4g,
                                               const float* __restrict__ W1, const float* __restrict__ b1,
                                               const float* __restrict__ g1, const float* __restrict__ be1,
                                               const float* __restrict__ W2, const float* __restrict__ b2,
                                               int* __restrict__ idx_out,
                                               float* __restrict__ s1sh, float* __restrict__ q1sh,
                                               unsigned int* __restrict__ ctr,
                                               unsigned int* __restrict__ W2fg, float* __restrict__ b2pg){
    __shared__ unsigned int hist[4][512][2];          // 16 KB: per-wave 512 buckets x2 replicas
    __shared__ unsigned long long lst[4][LISTCAP];    // 3.5 KB
    __shared__ int kidx[4][K_];                       // 0.5 KB  -> 20 KB total
    __shared__ float aa1s[H_], bb1s[H_];
    __shared__ int lastf;

    const int tid  = threadIdx.x;
    const int w    = tid >> 6;
    const int lane = tid & 63;
    const int half = lane >> 5;
    const int b    = blockIdx.x >> 9;
    const int q    = ((blockIdx.x & 511) << 2) + w;
    const int bN   = b * N_;
    unsigned int* hw = &hist[w][0][0];

    const uint4 z4 = make_uint4(0,0,0,0);
    uint4* h4 = (uint4*)hw;                           // 256 uint4 per wave
    #pragma unroll
    for (int i = 0; i < 4; ++i) h4[i*64 + lane] = z4;

    const float4 qp = xs4g[bN + q];
    const float qx = qp.x, qy = qp.y, qz = qp.z, sqq = qp.w;

    // pass 1: 32 candidates/lane, cache d-bits, linear histogram
    unsigned int fv[32];
    #pragma unroll
    for (int j = 0; j < 32; ++j){
        int c = j*64 + lane;
        float4 pt = xs4g[bN + c];
        float d = fmaf(-2.0f, dot3f(qx,qy,qz, pt.x,pt.y,pt.z), sqq) + pt.w;
        fv[j] = __float_as_uint(d);
        unsigned int u1 = __float_as_uint(d + 1.0f);
        unsigned int key = (u1 <= 0x3F800000u) ? 0u : ((u1 - 0x3F800000u) >> 15);
        key = key > 511u ? 511u : key;
        atomicAdd(&hw[key*2 + (lane & 1)], 1u);
    }

    // select: smallest bucket with cumulative >= K (lane covers 8 buckets)
    unsigned int g[8];
    #pragma unroll
    for (int t = 0; t < 4; ++t){
        uint4 h = ((const uint4*)hw)[lane*4 + t];
        g[2*t]   = h.x + h.y;
        g[2*t+1] = h.z + h.w;
    }
    unsigned int gs = 0;
    #pragma unroll
    for (int t = 0; t < 8; ++t) gs += g[t];
    unsigned int cum = gs;
    #pragma unroll
    for (int off = 1; off < 64; off <<= 1){
        unsigned int v = __shfl_up(cum, off);
        if (lane >= off) cum += v;
    }
    unsigned long long bal = __ballot(cum >= (unsigned)K_);
    int L = __ffsll(bal) - 1;
    unsigned int run = __shfl(cum, L) - __shfl(gs, L);
    int Bsel = 8*L + 7;
    {
        unsigned int c = run; bool fnd = false;
        #pragma unroll
        for (int t = 0; t < 8; ++t){
            unsigned int ht = __shfl(g[t], L, 64);
            if (!fnd && c + ht >= (unsigned)K_){ Bsel = 8*L + t; fnd = true; }
            c += ht;
        }
    }
    const float Tedge = __uint_as_float(0x3F800000u + ((unsigned)(Bsel + 1) << 15));
    const bool allin = (Bsel == 511);

    // pass 2: ballot-compaction of survivors (f1 < Tedge <=> bucket <= Bsel)
    const unsigned long long mlt = (lane == 63) ? ~0ull >> 1 : (1ull << lane) - 1ull;
    unsigned int cnt = 0;
    #pragma unroll
    for (int j = 0; j < 32; ++j){
        float f1 = __uint_as_float(fv[j]) + 1.0f;
        bool surv = (f1 < Tedge) || allin;
        unsigned long long sb = __ballot(surv);
        unsigned int pos = cnt + (unsigned int)__popcll(sb & mlt);
        if (surv && pos < (unsigned)LISTCAP)
            lst[w][pos] = ((unsigned long long)fv[j] << 32) | (unsigned int)(j*64 + lane);
        cnt += (unsigned int)__popcll(sb);
    }
    int m = (int)cnt; if (m > LISTCAP) m = LISTCAP;

    // rank-select (keys unique: idx in low bits) -> exact top_k tie-break
    int* outp = idx_out + ((size_t)bN + q) * K_;
    for (int i = lane; i < m; i += 64){
        unsigned long long my = lst[w][i];
        int rank = 0;
        for (int jj = 0; jj < m; ++jj)
            rank += (lst[w][jj] < my) ? 1 : 0;
        if (rank < K_){
            int id = (int)(unsigned int)(my & 0xFFFFFFFFull);
            outp[rank] = id;
            kidx[w][rank] = id;
        }
    }

    // fused h1 stats: ch = lane&31; halves split the 32 neighbors (16 each)
    {
        const int ch = lane & 31;
        float w1a = W1[ch], w1b = W1[H_+ch], w1c = W1[2*H_+ch], b1c = b1[ch];
        float s = 0.f, qq = 0.f;
        #pragma unroll
        for (int r = 0; r < 16; ++r){
            int idr = kidx[w][half*16 + r];            // wave-uniform LDS broadcast
            float4 pn = xs4g[bN + idr];
            float rx = pn.x - qx, ry = pn.y - qy, rz = pn.z - qz;
            float h = fmaxf(fmaf(rx, w1a, fmaf(ry, w1b, fmaf(rz, w1c, b1c))), 0.0f);
            s += h; qq = fmaf(h, h, qq);
        }
        s  += __shfl_xor(s, 32, 64);
        qq += __shfl_xor(qq, 32, 64);
        if (lane < 32){
            int sh = (blockIdx.x & (NSH-1)) * 32 + ch;
            atomicAdd(&s1sh[sh], s);
            atomicAdd(&q1sh[sh], qq);
        }
    }

    // ---- last-block tail: W2f frags + b2p (prep2 fold) ----
    __syncthreads();
    if (tid == 0){
        __threadfence();
        lastf = (atomicAdd(ctr, 1u) == (unsigned)gridDim.x - 1u) ? 1 : 0;
    }
    __syncthreads();
    if (lastf){
        if (tid < H_){
            float mm = shsum_at(s1sh, tid)*INVR_;
            float vv = shsum_at(q1sh, tid)*INVR_ - mm*mm;
            float a = g1[tid] / sqrtf(vv + EPS_);
            aa1s[tid] = a;
            bb1s[tid] = fmaf(-a, mm, be1[tid]);
        }
        __syncthreads();
        for (int d = tid; d < 512; d += 256){
            int jj = d & 3, ln = (d >> 2) & 63, s = d >> 8;
            int col = ln & 31;
            int k0 = s*16 + (ln >> 5)*8 + 2*jj;
            W2fg[d] = pk2(aa1s[k0]*W2[k0*H_ + col], aa1s[k0+1]*W2[(k0+1)*H_ + col]);
        }
        if (tid < H_){
            float acc = b2[tid];
            #pragma unroll 4
            for (int h = 0; h < H_; ++h) acc = fmaf(bb1s[h], W2[h*H_ + tid], acc);
            b2pg[tid] = acc;
        }
    }
}

// ---------------- h1 (raw) from xs4g ----------------
__device__ __forceinline__ void compute_h1v(const float4* __restrict__ xs4g, const int* __restrict__ idx, int r,
                                            const float* __restrict__ W1, const float* __restrict__ b1, float* h1){
    int b = r >> 16;
    int n = (r >> 5) & (N_-1);
    int id = idx[r];
    float4 pc = xs4g[b*N_ + n];
    float4 pn = xs4g[b*N_ + id];
    float rx = pn.x - pc.x, ry = pn.y - pc.y, rz = pn.z - pc.z;
    #pragma unroll
    for (int j = 0; j < H_; ++j){
        float a = fmaf(rx, W1[j], fmaf(ry, W1[H_+j], fmaf(rz, W1[2*H_+j], b1[j])));
        h1[j] = fmaxf(a, 0.0f);
    }
}

// ---- k_h2stats: h1 -> layer2 MFMA (split accs) -> relu -> stats; last block builds W3f (prep3 fold) ----
__global__ __launch_bounds__(256,4) void k_h2stats(const float4* __restrict__ xs4g, const int* __restrict__ idx,
                                                   const float* __restrict__ W1, const float* __restrict__ b1,
                                                   const uint4* __restrict__ W2f, const float* __restrict__ b2p,
                                                   const float* __restrict__ g2, const float* __restrict__ be2,
                                                   const float* __restrict__ W3, const float* __restrict__ b3,
                                                   float* gsum, float* gsq,
                                                   unsigned int* __restrict__ ctr,
                                                   unsigned int* __restrict__ W3f){
    __shared__ float redS[H_], redQ[H_];
    __shared__ int lastf;
    const int tid = threadIdx.x, lane = tid & 63;
    const int half = lane >> 5, m = lane & 31;
    if (tid < H_){ redS[tid] = 0.f; redQ[tid] = 0.f; }
    __syncthreads();

    int r = blockIdx.x*256 + tid;
    float h1[H_];
    compute_h1v(xs4g, idx, r, W1, b1, h1);
    unsigned int h1p[16];
    #pragma unroll
    for (int i = 0; i < 16; ++i) h1p[i] = pk2(h1[2*i], h1[2*i+1]);

    union { uint4 u4; f16x8 v; } Bf0, Bf1;
    Bf0.u4 = W2f[lane];
    Bf1.u4 = W2f[64 + lane];
    float b2c = b2p[m];

    float s = 0.f, q = 0.f;
    #pragma unroll
    for (int t = 0; t < 2; ++t){
        const int src = t*32 + m;
        union { unsigned int u[4]; f16x8 v; } a0, a1f;
        #pragma unroll
        for (int jj = 0; jj < 4; ++jj){
            unsigned int lo = __shfl(h1p[jj],     src, 64);
            unsigned int hi = __shfl(h1p[4 + jj], src, 64);
            a0.u[jj] = half ? hi : lo;
        }
        #pragma unroll
        for (int jj = 0; jj < 4; ++jj){
            unsigned int lo = __shfl(h1p[8 + jj],  src, 64);
            unsigned int hi = __shfl(h1p[12 + jj], src, 64);
            a1f.u[jj] = half ? hi : lo;
        }
        f32x16 acc0, acc1;
        #pragma unroll
        for (int i = 0; i < 16; ++i){ acc0[i] = b2c; acc1[i] = 0.f; }
        acc0 = __builtin_amdgcn_mfma_f32_32x32x16_f16(a0.v,  Bf0.v, acc0, 0, 0, 0);
        acc1 = __builtin_amdgcn_mfma_f32_32x32x16_f16(a1f.v, Bf1.v, acc1, 0, 0, 0);
        #pragma unroll
        for (int i = 0; i < 16; ++i){
            float v = fmaxf(acc0[i] + acc1[i], 0.0f);
            s += v; q = fmaf(v, v, q);
        }
    }
    s += __shfl_xor(s, 32, 64);
    q += __shfl_xor(q, 32, 64);
    if (lane < 32){ atomicAdd(&redS[m], s); atomicAdd(&redQ[m], q); }
    __syncthreads();
    if (tid < H_){ atomicAdd(&gsum[tid], redS[tid]); atomicAdd(&gsq[tid], redQ[tid]); }

    // ---- last-block tail: W3f build (verified pattern from R11) ----
    __syncthreads();
    if (tid == 0){
        __threadfence();
        lastf = (atomicAdd(ctr, 1u) == (unsigned)gridDim.x - 1u) ? 1 : 0;
    }
    __syncthreads();
    if (lastf){
        __shared__ float aa2[H_], bb2[H_];
        if (tid < H_){
            float sv = __hip_atomic_load(&gsum[tid], __ATOMIC_RELAXED, __HIP_MEMORY_SCOPE_AGENT);
            float qv = __hip_atomic_load(&gsq[tid],  __ATOMIC_RELAXED, __HIP_MEMORY_SCOPE_AGENT);
            float mm = sv*INVR_, vv = qv*INVR_ - mm*mm;
            float a = g2[tid] / sqrtf(vv + EPS_);
            aa2[tid] = a;
            bb2[tid] = fmaf(-a, mm, be2[tid]);
        }
        __syncthreads();
        for (int d = tid; d < 8448; d += 256){
            int jj = d & 3, ln = (d >> 2) & 63, step = d >> 8;
            int col = ln & 31;
            int off = (ln >> 5)*8 + 2*jj;
            float v0, v1;
            if (step < 32){
                v0 = aa2[step] * W3[step*512 + off*COUT_ + col];
                v1 = aa2[step] * W3[step*512 + (off+1)*COUT_ + col];
            } else {
                v0 = b3[off*COUT_ + col]; v1 = b3[(off+1)*COUT_ + col];
                #pragma unroll 4
                for (int h = 0; h < H_; ++h){
                    v0 = fmaf(bb2[h], W3[h*512 + off*COUT_ + col], v0);
                    v1 = fmaf(bb2[h], W3[h*512 + (off+1)*COUT_ + col], v1);
                }
            }
            W3f[d] = pk2(v0, v1);
        }
    }
}

// ---- k_out (FUSED): h1 -> layer2 MFMA swapped -> h2 in regs -> layer3 MFMA (2 indep acc chains) -> max ----
// W3 B-frags from GLOBAL (L1-resident; LDS staging regressed — round-9 lesson).
__global__ __launch_bounds__(256,3) void k_out(const float4* __restrict__ xs4g, const int* __restrict__ idx,
                                               const float* __restrict__ W1, const float* __restrict__ b1,
                                               const uint4* __restrict__ W2f, const float* __restrict__ b2p,
                                               const unsigned int* __restrict__ pf16,
                                               const uint4* __restrict__ W3f,
                                               float* __restrict__ out_pre, float* gsum, float* gsq){
    __shared__ float redS[COUT_], redQ[COUT_];
    const int tid = threadIdx.x, lane = tid & 63, w = tid >> 6;
    const int half = lane >> 5, m = lane & 31;
    if (tid < COUT_){ redS[tid] = 0.f; redQ[tid] = 0.f; }
    __syncthreads();

    const int rB = blockIdx.x*256 + w*64;
    int r = blockIdx.x*256 + tid;

    float h1[H_];
    compute_h1v(xs4g, idx, r, W1, b1, h1);
    unsigned int h1p[16];
    #pragma unroll
    for (int i = 0; i < 16; ++i) h1p[i] = pk2(h1[2*i], h1[2*i+1]);

    union { uint4 u4; f16x8 v; } A0, A1;     // W2'^T A-frags (same bits as W2f)
    A0.u4 = W2f[lane];
    A1.u4 = W2f[64 + lane];
    float b2v[16];                            // bias per C-reg: ch = (i&3)+8*(i>>2)+4*half
    #pragma unroll
    for (int i = 0; i < 16; ++i) b2v[i] = b2p[(i&3) + 8*(i>>2) + 4*half];

    const uint4* Wf = W3f + lane;

    #pragma unroll
    for (int t = 0; t < 2; ++t){
        const int src = t*32 + m;
        // B-frags = h1 of data-row t*32+m
        union { unsigned int u[4]; f16x8 v; } B0f, B1f;
        #pragma unroll
        for (int jj = 0; jj < 4; ++jj){
            unsigned int lo = __shfl(h1p[jj],     src, 64);
            unsigned int hi = __shfl(h1p[4 + jj], src, 64);
            B0f.u[jj] = half ? hi : lo;
        }
        #pragma unroll
        for (int jj = 0; jj < 4; ++jj){
            unsigned int lo = __shfl(h1p[8 + jj],  src, 64);
            unsigned int hi = __shfl(h1p[12 + jj], src, 64);
            B1f.u[jj] = half ? hi : lo;
        }
        f32x16 c2a, c2b;
        #pragma unroll
        for (int i = 0; i < 16; ++i){ c2a[i] = b2v[i]; c2b[i] = 0.f; }
        c2a = __builtin_amdgcn_mfma_f32_32x32x16_f16(A0.v, B0f.v, c2a, 0, 0, 0);
        c2b = __builtin_amdgcn_mfma_f32_32x32x16_f16(A1.v, B1f.v, c2b, 0, 0, 0);

        // relu + pack + half-exchange -> h2p[16] = row (t*32+m)'s 32 channels, f16-packed
        unsigned int h2p[16];
        #pragma unroll
        for (int p = 0; p < 8; ++p){
            float v0 = fmaxf(c2a[2*p]   + c2b[2*p],   0.0f);
            float v1 = fmaxf(c2a[2*p+1] + c2b[2*p+1], 0.0f);
            unsigned int ow = pk2(v0, v1);
            unsigned int ot = __shfl_xor(ow, 32, 64);
            int a = p >> 1, bb = p & 1;
            h2p[4*a + 2*half     + bb] = ow;
            h2p[4*a + 2*(1-half) + bb] = ot;
        }

        // gp for row t*32+m
        int row = rB + t*32 + m;
        int bb_ = row >> 16;
        int idr = idx[row];
        const uint4* gpp = (const uint4*)(pf16 + ((size_t)bb_*N_ + idr)*8);
        uint4 ga = gpp[0], gb = gpp[1];
        unsigned int gsel[4];
        gsel[0] = half ? gb.x : ga.x;
        gsel[1] = half ? gb.y : ga.y;
        gsel[2] = half ? gb.z : ga.z;
        gsel[3] = half ? gb.w : ga.w;

        // two independent MFMA chains (even/odd kb) halve the dependent-MFMA critical path
        f32x16 acca, accb;
        #pragma unroll
        for (int i = 0; i < 16; ++i){ acca[i] = 0.f; accb[i] = 0.f; }
        #pragma unroll
        for (int kb = 0; kb < 32; kb += 2){
            unsigned int hr = h2p[kb >> 1];
            unsigned int hd0 = __builtin_amdgcn_perm(hr, hr, 0x01000100u);
            unsigned int hd1 = __builtin_amdgcn_perm(hr, hr, 0x03020302u);
            union { unsigned int u[4]; f16x8 v; } af0, af1;
            #pragma unroll
            for (int jj = 0; jj < 4; ++jj){ af0.u[jj] = pkmul(hd0, gsel[jj]); af1.u[jj] = pkmul(hd1, gsel[jj]); }
            union { uint4 u4; f16x8 v; } bf0, bf1;
            bf0.u4 = Wf[kb*64];
            bf1.u4 = Wf[(kb+1)*64];
            acca = __builtin_amdgcn_mfma_f32_32x32x16_f16(af0.v, bf0.v, acca, 0, 0, 0);
            accb = __builtin_amdgcn_mfma_f32_32x32x16_f16(af1.v, bf1.v, accb, 0, 0, 0);
        }
        {   // bias step: A = gp, B = b3'
            union { unsigned int u[4]; f16x8 v; } af;
            #pragma unroll
            for (int jj = 0; jj < 4; ++jj) af.u[jj] = gsel[jj];
            union { uint4 u4; f16x8 v; } bf; bf.u4 = Wf[32*64];
            acca = __builtin_amdgcn_mfma_f32_32x32x16_f16(af.v, bf.v, acca, 0, 0, 0);
        }

        float v = acca[0] + accb[0];
        #pragma unroll
        for (int i = 1; i < 16; ++i) v = fmaxf(v, acca[i] + accb[i]);
        v = fmaxf(v, __shfl_xor(v, 32, 64));
        if (lane < 32){
            int g = blockIdx.x*8 + w*2 + t;
            out_pre[(size_t)g*COUT_ + m] = v;
            atomicAdd(&redS[m], v);
            atomicAdd(&redQ[m], v*v);
        }
    }
    __syncthreads();
    if (tid < COUT_){ atomicAdd(&gsum[tid], redS[tid]); atomicAdd(&gsq[tid], redQ[tid]); }
}

__global__ __launch_bounds__(256) void k_bn(const float* __restrict__ out_pre,
                                            const float* __restrict__ s3, const float* __restrict__ q3,
                                            const float* __restrict__ gbn, const float* __restrict__ bbn,
                                            float* __restrict__ out){
    int i = blockIdx.x*256 + threadIdx.x;
    int o = i & (COUT_-1);
    float mm = s3[o] * INVBN_;
    float vv = q3[o] * INVBN_ - mm*mm;
    float aa = gbn[o] / sqrtf(vv + EPS_);
    out[i] = fmaf(aa, out_pre[i], fmaf(-aa, mm, bbn[o]));
}

extern "C" void kernel_launch(void* const* d_in, const int* in_sizes, int n_in,
                              void* d_out, int out_size, void* d_ws, size_t ws_size,
                              hipStream_t stream){
    const float* xyz    = (const float*)d_in[0];
    const float* points = (const float*)d_in[1];
    const float* W1  = (const float*)d_in[2];
    const float* b1  = (const float*)d_in[3];
    const float* g1  = (const float*)d_in[4];
    const float* be1 = (const float*)d_in[5];
    const float* W2  = (const float*)d_in[6];
    const float* b2  = (const float*)d_in[7];
    const float* g2  = (const float*)d_in[8];
    const float* be2 = (const float*)d_in[9];
    const float* W3  = (const float*)d_in[10];
    const float* b3  = (const float*)d_in[11];
    const float* gbn = (const float*)d_in[12];
    const float* bbn = (const float*)d_in[13];
    float* out = (float*)d_out;

    // ws layout (bytes), ~2.6 MB total
    char* base = (char*)d_ws;
    int*            idx     = (int*)(base + 0);                     // 1,048,576
    float*          out_pre = (float*)(base + 1048576);             // 1,048,576
    unsigned int*   pf16    = (unsigned int*)(base + 2097152);      //    262,144
    unsigned int*   W3f     = (unsigned int*)(base + 2359296);      //     33,792
    float*          st      = (float*)(base + 2393088);             //      5,120
    float4*         xs4g    = (float4*)(base + 2398208);            //    131,072
    unsigned int*   W2fg    = (unsigned int*)(base + 2529280);      //      2,048
    float*          b2pg    = (float*)(base + 2531328);             //        128
    // st floats: s1s[512] | q1s[512] | s2[32] | q2[32] | s3[32] | q3[32] | ctr1 | ctr2
    float *s1s=st, *q1s=st+512, *s2=st+1024, *q2=st+1056, *s3=st+1088, *q3=st+1120;
    unsigned int* ctr1 = (unsigned int*)(st + 1152);
    unsigned int* ctr2 = (unsigned int*)(st + 1153);

    hipLaunchKernelGGL(k_prep0,   dim3(256),     dim3(256), 0, stream, xyz, points, xs4g, pf16, st);
    hipLaunchKernelGGL(k_knn,     dim3(B_*N_/4), dim3(256), 0, stream, xs4g, W1, b1, g1, be1, W2, b2,
                       idx, s1s, q1s, ctr1, W2fg, b2pg);
    hipLaunchKernelGGL(k_h2stats, dim3(R_/256),  dim3(256), 0, stream, xs4g, idx, W1, b1,
                       (const uint4*)W2fg, b2pg, g2, be2, W3, b3, s2, q2, ctr2, W3f);
    hipLaunchKernelGGL(k_out,     dim3(R_/256),  dim3(256), 0, stream, xs4g, idx, W1, b1,
                       (const uint4*)W2fg, b2pg, pf16, (const uint4*)W3f, out_pre, s3, q3);
    hipLaunchKernelGGL(k_bn,      dim3(B_*N_*COUT_/256), dim3(256), 0, stream, out_pre, s3, q3, gbn, bbn, out);
}

// Round 14
// 198.986 us; speedup vs baseline: 2.2698x; 1.1871x over previous
//
#include <hip/hip_runtime.h>

#define B_ 4
#define N_ 2048
#define K_ 32
#define CIN_ 16
#define COUT_ 32
#define H_ 32
#define R_ (B_*N_*K_)      // 262144 rows through the weight-net
#define EPS_ 1e-5f
#define INVR_ (1.0f/(float)R_)
#define INVBN_ (1.0f/(float)(B_*N_))
#define LISTCAP 112
#define NSH 16             // stat shadows

typedef __attribute__((ext_vector_type(8)))  _Float16 f16x8;
typedef __attribute__((ext_vector_type(2)))  __fp16   hw16x2;   // builtin cvt_pkrtz return type
typedef __attribute__((ext_vector_type(2)))  _Float16 f16x2;
typedef __attribute__((ext_vector_type(16))) float    f32x16;

__device__ __forceinline__ float dot3f(float ax,float ay,float az,float bx,float by,float bz){
    return fmaf(az,bz, fmaf(ay,by, ax*bx));
}
__device__ __forceinline__ unsigned int pk2(float a, float b){   // packed f16 pair (RTZ)
    union { hw16x2 v; unsigned int u; } c;
    c.v = __builtin_amdgcn_cvt_pkrtz(a, b);
    return c.u;
}
__device__ __forceinline__ unsigned int pkmul(unsigned int a, unsigned int b){  // v_pk_mul_f16
    union { unsigned int u; f16x2 v; } x, y, r;
    x.u = a; y.u = b; r.v = x.v * y.v; return r.u;
}
// sum of NSH shadow accumulators
__device__ __forceinline__ float shsum(const float* __restrict__ p, int k){
    float s = 0.f;
    #pragma unroll
    for (int i = 0; i < NSH; ++i) s += p[i*32 + k];
    return s;
}

// ---- prep0: pf16 (points->f16 pairs), xs4g, zero stats ----
__global__ __launch_bounds__(256) void k_prep0(const float* __restrict__ xyz, const float* __restrict__ points,
                                               float4* __restrict__ xs4g, unsigned int* __restrict__ pf16,
                                               float* __restrict__ st){
    int i = blockIdx.x*256 + threadIdx.x;      // 256 blocks x 256 = 65536
    pf16[i] = pk2(points[2*i], points[2*i+1]);
    if (i < 8192){
        float x = xyz[3*i], y = xyz[3*i+1], z = xyz[3*i+2];
        xs4g[i] = make_float4(x, y, z, dot3f(x,y,z,x,y,z));
    }
    if (blockIdx.x == 0){
        for (int j = threadIdx.x; j < 1280; j += 256) st[j] = 0.f;
    }
}

// ---------------- KNN: 1 wave/query, wave-autonomous, single-pass linear-bucket histogram ----------------
// (256,6): (256,8) capped VGPR at 64 -> pass-1's 32 float4 loads lost MLP (round-9 lesson).
// NO tail code: R13 showed any appended phase perturbs the allocator (44->40 VGPR, dur 2x).
__global__ __launch_bounds__(256,6) void k_knn(const float4* __restrict__ xs4g,
                                               const float* __restrict__ W1, const float* __restrict__ b1,
                                               int* __restrict__ idx_out,
                                               float* __restrict__ s1sh, float* __restrict__ q1sh){
    __shared__ unsigned int hist[4][512][2];          // 16 KB: per-wave 512 buckets x2 replicas
    __shared__ unsigned long long lst[4][LISTCAP];    // 3.5 KB
    __shared__ int kidx[4][K_];                       // 0.5 KB  -> 20 KB total

    const int tid  = threadIdx.x;
    const int w    = tid >> 6;
    const int lane = tid & 63;
    const int half = lane >> 5;
    const int b    = blockIdx.x >> 9;
    const int q    = ((blockIdx.x & 511) << 2) + w;
    const int bN   = b * N_;
    unsigned int* hw = &hist[w][0][0];

    const uint4 z4 = make_uint4(0,0,0,0);
    uint4* h4 = (uint4*)hw;                           // 256 uint4 per wave
    #pragma unroll
    for (int i = 0; i < 4; ++i) h4[i*64 + lane] = z4;

    const float4 qp = xs4g[bN + q];
    const float qx = qp.x, qy = qp.y, qz = qp.z, sqq = qp.w;

    // pass 1: 32 candidates/lane, cache d-bits, linear histogram
    unsigned int fv[32];
    #pragma unroll
    for (int j = 0; j < 32; ++j){
        int c = j*64 + lane;
        float4 pt = xs4g[bN + c];
        float d = fmaf(-2.0f, dot3f(qx,qy,qz, pt.x,pt.y,pt.z), sqq) + pt.w;
        fv[j] = __float_as_uint(d);
        unsigned int u1 = __float_as_uint(d + 1.0f);
        unsigned int key = (u1 <= 0x3F800000u) ? 0u : ((u1 - 0x3F800000u) >> 15);
        key = key > 511u ? 511u : key;
        atomicAdd(&hw[key*2 + (lane & 1)], 1u);
    }

    // select: smallest bucket with cumulative >= K (lane covers 8 buckets)
    unsigned int g[8];
    #pragma unroll
    for (int t = 0; t < 4; ++t){
        uint4 h = ((const uint4*)hw)[lane*4 + t];
        g[2*t]   = h.x + h.y;
        g[2*t+1] = h.z + h.w;
    }
    unsigned int gs = 0;
    #pragma unroll
    for (int t = 0; t < 8; ++t) gs += g[t];
    unsigned int cum = gs;
    #pragma unroll
    for (int off = 1; off < 64; off <<= 1){
        unsigned int v = __shfl_up(cum, off);
        if (lane >= off) cum += v;
    }
    unsigned long long bal = __ballot(cum >= (unsigned)K_);
    int L = __ffsll(bal) - 1;
    unsigned int run = __shfl(cum, L) - __shfl(gs, L);
    int Bsel = 8*L + 7;
    {
        unsigned int c = run; bool fnd = false;
        #pragma unroll
        for (int t = 0; t < 8; ++t){
            unsigned int ht = __shfl(g[t], L, 64);
            if (!fnd && c + ht >= (unsigned)K_){ Bsel = 8*L + t; fnd = true; }
            c += ht;
        }
    }
    const float Tedge = __uint_as_float(0x3F800000u + ((unsigned)(Bsel + 1) << 15));
    const bool allin = (Bsel == 511);

    // pass 2: ballot-compaction of survivors (f1 < Tedge <=> bucket <= Bsel)
    const unsigned long long mlt = (lane == 63) ? ~0ull >> 1 : (1ull << lane) - 1ull;
    unsigned int cnt = 0;
    #pragma unroll
    for (int j = 0; j < 32; ++j){
        float f1 = __uint_as_float(fv[j]) + 1.0f;
        bool surv = (f1 < Tedge) || allin;
        unsigned long long sb = __ballot(surv);
        unsigned int pos = cnt + (unsigned int)__popcll(sb & mlt);
        if (surv && pos < (unsigned)LISTCAP)
            lst[w][pos] = ((unsigned long long)fv[j] << 32) | (unsigned int)(j*64 + lane);
        cnt += (unsigned int)__popcll(sb);
    }
    int m = (int)cnt; if (m > LISTCAP) m = LISTCAP;

    // rank-select (keys unique: idx in low bits) -> exact top_k tie-break
    int* outp = idx_out + ((size_t)bN + q) * K_;
    for (int i = lane; i < m; i += 64){
        unsigned long long my = lst[w][i];
        int rank = 0;
        for (int jj = 0; jj < m; ++jj)
            rank += (lst[w][jj] < my) ? 1 : 0;
        if (rank < K_){
            int id = (int)(unsigned int)(my & 0xFFFFFFFFull);
            outp[rank] = id;
            kidx[w][rank] = id;
        }
    }

    // fused h1 stats: ch = lane&31; halves split the 32 neighbors (16 each)
    {
        const int ch = lane & 31;
        float w1a = W1[ch], w1b = W1[H_+ch], w1c = W1[2*H_+ch], b1c = b1[ch];
        float s = 0.f, qq = 0.f;
        #pragma unroll
        for (int r = 0; r < 16; ++r){
            int idr = kidx[w][half*16 + r];            // wave-uniform LDS broadcast
            float4 pn = xs4g[bN + idr];
            float rx = pn.x - qx, ry = pn.y - qy, rz = pn.z - qz;
            float h = fmaxf(fmaf(rx, w1a, fmaf(ry, w1b, fmaf(rz, w1c, b1c))), 0.0f);
            s += h; qq = fmaf(h, h, qq);
        }
        s  += __shfl_xor(s, 32, 64);
        qq += __shfl_xor(qq, 32, 64);
        if (lane < 32){
            int sh = (blockIdx.x & (NSH-1)) * 32 + ch;
            atomicAdd(&s1sh[sh], s);
            atomicAdd(&q1sh[sh], qq);
        }
    }
}

// ---------------- h1 (raw) from xs4g ----------------
__device__ __forceinline__ void compute_h1v(const float4* __restrict__ xs4g, const int* __restrict__ idx, int r,
                                            const float* __restrict__ W1, const float* __restrict__ b1, float* h1){
    int b = r >> 16;
    int n = (r >> 5) & (N_-1);
    int id = idx[r];
    float4 pc = xs4g[b*N_ + n];
    float4 pn = xs4g[b*N_ + id];
    float rx = pn.x - pc.x, ry = pn.y - pc.y, rz = pn.z - pc.z;
    #pragma unroll
    for (int j = 0; j < H_; ++j){
        float a = fmaf(rx, W1[j], fmaf(ry, W1[H_+j], fmaf(rz, W1[2*H_+j], b1[j])));
        h1[j] = fmaxf(a, 0.0f);
    }
}

// ---- prep2: W2' = a1(.)W2 f16 frags; b2' = b2 + bb1@W2 (shadow-summed s1/q1) ----
__global__ __launch_bounds__(256) void k_prep2(const float* __restrict__ s1s, const float* __restrict__ q1s,
                                               const float* __restrict__ g1, const float* __restrict__ be1,
                                               const float* __restrict__ W2, const float* __restrict__ b2,
                                               unsigned int* __restrict__ W2f, float* __restrict__ b2p){
    int flat = blockIdx.x*256 + threadIdx.x;   // 3 blocks
    if (flat < 512){
        int d = flat;
        int jj = d & 3, lane = (d >> 2) & 63, s = d >> 8;
        int col = lane & 31;
        int k0 = s*16 + (lane >> 5)*8 + 2*jj;
        float m0 = shsum(s1s,k0)*INVR_,   v0 = shsum(q1s,k0)*INVR_   - m0*m0;
        float m1 = shsum(s1s,k0+1)*INVR_, v1 = shsum(q1s,k0+1)*INVR_ - m1*m1;
        float a0  = g1[k0]   / sqrtf(v0 + EPS_);
        float a1v = g1[k0+1] / sqrtf(v1 + EPS_);
        W2f[d] = pk2(a0*W2[k0*H_ + col], a1v*W2[(k0+1)*H_ + col]);
    } else if (flat < 544){
        int col = flat - 512;
        float acc = b2[col];
        #pragma unroll 4
        for (int h = 0; h < H_; ++h){
            float mm = shsum(s1s,h)*INVR_, vv = shsum(q1s,h)*INVR_ - mm*mm;
            float aa = g1[h] / sqrtf(vv + EPS_);
            float bb = fmaf(-aa, mm, be1[h]);
            acc = fmaf(bb, W2[h*H_ + col], acc);
        }
        b2p[col] = acc;
    }
}

// ---- k_h2stats: h1 -> layer2 MFMA (C[row][ch]) -> relu -> per-channel stats ONLY ----
__global__ __launch_bounds__(256,4) void k_h2stats(const float4* __restrict__ xs4g, const int* __restrict__ idx,
                                                   const float* __restrict__ W1, const float* __restrict__ b1,
                                                   const uint4* __restrict__ W2f, const float* __restrict__ b2p,
                                                   float* gsum, float* gsq){
    __shared__ float redS[H_], redQ[H_];
    const int tid = threadIdx.x, lane = tid & 63, w = tid >> 6;
    const int half = lane >> 5, m = lane & 31;
    if (tid < H_){ redS[tid] = 0.f; redQ[tid] = 0.f; }
    __syncthreads();

    int r = blockIdx.x*256 + tid;
    float h1[H_];
    compute_h1v(xs4g, idx, r, W1, b1, h1);
    unsigned int h1p[16];
    #pragma unroll
    for (int i = 0; i < 16; ++i) h1p[i] = pk2(h1[2*i], h1[2*i+1]);

    union { uint4 u4; f16x8 v; } Bf0, Bf1;
    Bf0.u4 = W2f[lane];
    Bf1.u4 = W2f[64 + lane];
    float b2c = b2p[m];

    float s = 0.f, q = 0.f;
    #pragma unroll
    for (int t = 0; t < 2; ++t){
        const int src = t*32 + m;
        union { unsigned int u[4]; f16x8 v; } a0, a1f;
        #pragma unroll
        for (int jj = 0; jj < 4; ++jj){
            unsigned int lo = __shfl(h1p[jj],     src, 64);
            unsigned int hi = __shfl(h1p[4 + jj], src, 64);
            a0.u[jj] = half ? hi : lo;
        }
        #pragma unroll
        for (int jj = 0; jj < 4; ++jj){
            unsigned int lo = __shfl(h1p[8 + jj],  src, 64);
            unsigned int hi = __shfl(h1p[12 + jj], src, 64);
            a1f.u[jj] = half ? hi : lo;
        }
        f32x16 acc;
        #pragma unroll
        for (int i = 0; i < 16; ++i) acc[i] = b2c;
        acc = __builtin_amdgcn_mfma_f32_32x32x16_f16(a0.v,  Bf0.v, acc, 0, 0, 0);
        acc = __builtin_amdgcn_mfma_f32_32x32x16_f16(a1f.v, Bf1.v, acc, 0, 0, 0);
        #pragma unroll
        for (int i = 0; i < 16; ++i){
            float v = fmaxf(acc[i], 0.0f);
            s += v; q = fmaf(v, v, q);
        }
    }
    s += __shfl_xor(s, 32, 64);
    q += __shfl_xor(q, 32, 64);
    if (lane < 32){ atomicAdd(&redS[m], s); atomicAdd(&redQ[m], q); }
    __syncthreads();
    if (tid < H_){ atomicAdd(&gsum[tid], redS[tid]); atomicAdd(&gsq[tid], redQ[tid]); }
}

// ---- prep3: W3'' = aa2(.)W3 (+ b3' bias row at step 32) -> f16 B-frags for K=528 ----
__global__ __launch_bounds__(256) void k_prep3(const float* __restrict__ W3, const float* __restrict__ b3,
                                               const float* __restrict__ s2, const float* __restrict__ q2,
                                               const float* __restrict__ g2, const float* __restrict__ be2,
                                               unsigned int* __restrict__ W3f){
    int d = blockIdx.x*256 + threadIdx.x;     // 33*256 = 8448 dwords
    int jj = d & 3, lane = (d >> 2) & 63, step = d >> 8;
    int col = lane & 31;
    int off = (lane >> 5)*8 + 2*jj;
    float v0, v1;
    if (step < 32){
        int h = step, c0 = off;
        float mm = s2[h]*INVR_, vv = q2[h]*INVR_ - mm*mm;
        float aa = g2[h] / sqrtf(vv + EPS_);
        v0 = aa * W3[h*512 + c0*COUT_ + col];
        v1 = aa * W3[h*512 + (c0+1)*COUT_ + col];
    } else {
        int c0 = off;
        v0 = b3[c0*COUT_ + col]; v1 = b3[(c0+1)*COUT_ + col];
        #pragma unroll 4
        for (int h = 0; h < H_; ++h){
            float mm = s2[h]*INVR_, vv = q2[h]*INVR_ - mm*mm;
            float aa = g2[h] / sqrtf(vv + EPS_);
            float bb = fmaf(-aa, mm, be2[h]);
            v0 = fmaf(bb, W3[h*512 + c0*COUT_ + col], v0);
            v1 = fmaf(bb, W3[h*512 + (c0+1)*COUT_ + col], v1);
        }
    }
    W3f[d] = pk2(v0, v1);
}

// ---- k_out (FUSED): h1 -> layer2 MFMA swapped -> h2 in regs -> layer3 MFMA (2 indep acc chains) -> max ----
// W3 B-frags from GLOBAL (L1-resident; LDS staging regressed — round-9 lesson).
// ONLY change vs R10: the 33-step dependent MFMA chain split into even/odd accumulators (latency halving).
__global__ __launch_bounds__(256,3) void k_out(const float4* __restrict__ xs4g, const int* __restrict__ idx,
                                               const float* __restrict__ W1, const float* __restrict__ b1,
                                               const uint4* __restrict__ W2f, const float* __restrict__ b2p,
                                               const unsigned int* __restrict__ pf16,
                                               const uint4* __restrict__ W3f,
                                               float* __restrict__ out_pre, float* gsum, float* gsq){
    __shared__ float redS[COUT_], redQ[COUT_];
    const int tid = threadIdx.x, lane = tid & 63, w = tid >> 6;
    const int half = lane >> 5, m = lane & 31;
    if (tid < COUT_){ redS[tid] = 0.f; redQ[tid] = 0.f; }
    __syncthreads();

    const int rB = blockIdx.x*256 + w*64;
    int r = blockIdx.x*256 + tid;

    float h1[H_];
    compute_h1v(xs4g, idx, r, W1, b1, h1);
    unsigned int h1p[16];
    #pragma unroll
    for (int i = 0; i < 16; ++i) h1p[i] = pk2(h1[2*i], h1[2*i+1]);

    union { uint4 u4; f16x8 v; } A0, A1;     // W2'^T A-frags (same bits as W2f)
    A0.u4 = W2f[lane];
    A1.u4 = W2f[64 + lane];
    float b2v[16];                            // bias per C-reg: ch = (i&3)+8*(i>>2)+4*half
    #pragma unroll
    for (int i = 0; i < 16; ++i) b2v[i] = b2p[(i&3) + 8*(i>>2) + 4*half];

    const uint4* Wf = W3f + lane;

    #pragma unroll
    for (int t = 0; t < 2; ++t){
        const int src = t*32 + m;
        // B-frags = h1 of data-row t*32+m
        union { unsigned int u[4]; f16x8 v; } B0f, B1f;
        #pragma unroll
        for (int jj = 0; jj < 4; ++jj){
            unsigned int lo = __shfl(h1p[jj],     src, 64);
            unsigned int hi = __shfl(h1p[4 + jj], src, 64);
            B0f.u[jj] = half ? hi : lo;
        }
        #pragma unroll
        for (int jj = 0; jj < 4; ++jj){
            unsigned int lo = __shfl(h1p[8 + jj],  src, 64);
            unsigned int hi = __shfl(h1p[12 + jj], src, 64);
            B1f.u[jj] = half ? hi : lo;
        }
        f32x16 c2;
        #pragma unroll
        for (int i = 0; i < 16; ++i) c2[i] = b2v[i];
        c2 = __builtin_amdgcn_mfma_f32_32x32x16_f16(A0.v, B0f.v, c2, 0, 0, 0);
        c2 = __builtin_amdgcn_mfma_f32_32x32x16_f16(A1.v, B1f.v, c2, 0, 0, 0);

        // relu + pack + half-exchange -> h2p[16] = row (t*32+m)'s 32 channels, f16-packed
        unsigned int h2p[16];
        #pragma unroll
        for (int p = 0; p < 8; ++p){
            float v0 = fmaxf(c2[2*p],   0.0f);
            float v1 = fmaxf(c2[2*p+1], 0.0f);
            unsigned int ow = pk2(v0, v1);
            unsigned int ot = __shfl_xor(ow, 32, 64);
            int a = p >> 1, bb = p & 1;
            h2p[4*a + 2*half     + bb] = ow;
            h2p[4*a + 2*(1-half) + bb] = ot;
        }

        // gp for row t*32+m
        int row = rB + t*32 + m;
        int bb_ = row >> 16;
        int idr = idx[row];
        const uint4* gpp = (const uint4*)(pf16 + ((size_t)bb_*N_ + idr)*8);
        uint4 ga = gpp[0], gb = gpp[1];
        unsigned int gsel[4];
        gsel[0] = half ? gb.x : ga.x;
        gsel[1] = half ? gb.y : ga.y;
        gsel[2] = half ? gb.z : ga.z;
        gsel[3] = half ? gb.w : ga.w;

        // two independent MFMA chains (even/odd kb) halve the dependent-MFMA critical path
        f32x16 acca, accb;
        #pragma unroll
        for (int i = 0; i < 16; ++i){ acca[i] = 0.f; accb[i] = 0.f; }
        #pragma unroll
        for (int kb = 0; kb < 32; kb += 2){
            unsigned int hr = h2p[kb >> 1];
            unsigned int hd0 = __builtin_amdgcn_perm(hr, hr, 0x01000100u);
            unsigned int hd1 = __builtin_amdgcn_perm(hr, hr, 0x03020302u);
            union { unsigned int u[4]; f16x8 v; } af0, af1;
            #pragma unroll
            for (int jj = 0; jj < 4; ++jj){ af0.u[jj] = pkmul(hd0, gsel[jj]); af1.u[jj] = pkmul(hd1, gsel[jj]); }
            union { uint4 u4; f16x8 v; } bf0, bf1;
            bf0.u4 = Wf[kb*64];
            bf1.u4 = Wf[(kb+1)*64];
            acca = __builtin_amdgcn_mfma_f32_32x32x16_f16(af0.v, bf0.v, acca, 0, 0, 0);
            accb = __builtin_amdgcn_mfma_f32_32x32x16_f16(af1.v, bf1.v, accb, 0, 0, 0);
        }
        {   // bias step: A = gp, B = b3'
            union { unsigned int u[4]; f16x8 v; } af;
            #pragma unroll
            for (int jj = 0; jj < 4; ++jj) af.u[jj] = gsel[jj];
            union { uint4 u4; f16x8 v; } bf; bf.u4 = Wf[32*64];
            acca = __builtin_amdgcn_mfma_f32_32x32x16_f16(af.v, bf.v, acca, 0, 0, 0);
        }

        float v = acca[0] + accb[0];
        #pragma unroll
        for (int i = 1; i < 16; ++i) v = fmaxf(v, acca[i] + accb[i]);
        v = fmaxf(v, __shfl_xor(v, 32, 64));
        if (lane < 32){
            int g = blockIdx.x*8 + w*2 + t;
            out_pre[(size_t)g*COUT_ + m] = v;
            atomicAdd(&redS[m], v);
            atomicAdd(&redQ[m], v*v);
        }
    }
    __syncthreads();
    if (tid < COUT_){ atomicAdd(&gsum[tid], redS[tid]); atomicAdd(&gsq[tid], redQ[tid]); }
}

__global__ __launch_bounds__(256) void k_bn(const float* __restrict__ out_pre,
                                            const float* __restrict__ s3, const float* __restrict__ q3,
                                            const float* __restrict__ gbn, const float* __restrict__ bbn,
                                            float* __restrict__ out){
    int i = blockIdx.x*256 + threadIdx.x;
    int o = i & (COUT_-1);
    float mm = s3[o] * INVBN_;
    float vv = q3[o] * INVBN_ - mm*mm;
    float aa = gbn[o] / sqrtf(vv + EPS_);
    out[i] = fmaf(aa, out_pre[i], fmaf(-aa, mm, bbn[o]));
}

extern "C" void kernel_launch(void* const* d_in, const int* in_sizes, int n_in,
                              void* d_out, int out_size, void* d_ws, size_t ws_size,
                              hipStream_t stream){
    const float* xyz    = (const float*)d_in[0];
    const float* points = (const float*)d_in[1];
    const float* W1  = (const float*)d_in[2];
    const float* b1  = (const float*)d_in[3];
    const float* g1  = (const float*)d_in[4];
    const float* be1 = (const float*)d_in[5];
    const float* W2  = (const float*)d_in[6];
    const float* b2  = (const float*)d_in[7];
    const float* g2  = (const float*)d_in[8];
    const float* be2 = (const float*)d_in[9];
    const float* W3  = (const float*)d_in[10];
    const float* b3  = (const float*)d_in[11];
    const float* gbn = (const float*)d_in[12];
    const float* bbn = (const float*)d_in[13];
    float* out = (float*)d_out;

    // ws layout (bytes), ~2.6 MB total
    char* base = (char*)d_ws;
    int*            idx     = (int*)(base + 0);                     // 1,048,576
    float*          out_pre = (float*)(base + 1048576);             // 1,048,576
    unsigned int*   pf16    = (unsigned int*)(base + 2097152);      //    262,144
    unsigned int*   W3f     = (unsigned int*)(base + 2359296);      //     33,792
    float*          st      = (float*)(base + 2393088);             //      5,120
    float4*         xs4g    = (float4*)(base + 2398208);            //    131,072
    unsigned int*   W2fg    = (unsigned int*)(base + 2529280);      //      2,048
    float*          b2pg    = (float*)(base + 2531328);             //        128
    // st floats: s1s[512] | q1s[512] | s2[32] | q2[32] | s3[32] | q3[32]
    float *s1s=st, *q1s=st+512, *s2=st+1024, *q2=st+1056, *s3=st+1088, *q3=st+1120;

    hipLaunchKernelGGL(k_prep0,   dim3(256),     dim3(256), 0, stream, xyz, points, xs4g, pf16, st);
    hipLaunchKernelGGL(k_knn,     dim3(B_*N_/4), dim3(256), 0, stream, xs4g, W1, b1, idx, s1s, q1s);
    hipLaunchKernelGGL(k_prep2,   dim3(3),       dim3(256), 0, stream, s1s, q1s, g1, be1, W2, b2, W2fg, b2pg);
    hipLaunchKernelGGL(k_h2stats, dim3(R_/256),  dim3(256), 0, stream, xs4g, idx, W1, b1,
                       (const uint4*)W2fg, b2pg, s2, q2);
    hipLaunchKernelGGL(k_prep3,   dim3(33),      dim3(256), 0, stream, W3, b3, s2, q2, g2, be2, W3f);
    hipLaunchKernelGGL(k_out,     dim3(R_/256),  dim3(256), 0, stream, xs4g, idx, W1, b1,
                       (const uint4*)W2fg, b2pg, pf16, (const uint4*)W3f, out_pre, s3, q3);
    hipLaunchKernelGGL(k_bn,      dim3(B_*N_*COUT_/256), dim3(256), 0, stream, out_pre, s3, q3, gbn, bbn, out);
}